// Round 4
// baseline (844.042 us; speedup 1.0000x reference)
//
#include <hip/hip_runtime.h>

#define B_  8
#define T_  4096
#define C_  1024
#define H_  16
#define D_  64
#define C3_ 3072

typedef __attribute__((ext_vector_type(4))) float f32x4;
typedef __attribute__((ext_vector_type(8))) __bf16 bf16x8;
typedef __attribute__((ext_vector_type(4))) unsigned short us4;
typedef __attribute__((ext_vector_type(8))) unsigned short us8;

__device__ __forceinline__ float b2f(unsigned short u) {
  return __uint_as_float(((unsigned)u) << 16);
}
__device__ __forceinline__ unsigned short f2bf(float f) {
  unsigned u = __float_as_uint(f);
  u += 0x7fffu + ((u >> 16) & 1u);
  return (unsigned short)(u >> 16);
}
__device__ __forceinline__ void gload16(const void* g, void* l) {
  __builtin_amdgcn_global_load_lds(
      (const __attribute__((address_space(1))) void*)g,
      (__attribute__((address_space(3))) void*)l, 16, 0, 0);
}

// ---------------- pre-passes ----------------

// x [B][C][T] f32 -> xbt [B][T][C] bf16
__global__ __launch_bounds__(256) void transpose_x(const float* __restrict__ x,
                                                   unsigned short* __restrict__ xbt) {
  __shared__ float tile[64][65];
  const int tid = threadIdx.x;
  const int t0 = blockIdx.x * 64, c0 = blockIdx.y * 64, b = blockIdx.z;
  const int col = tid & 63, rr = tid >> 6;
  const float* xb = x + ((size_t)b * C_ + c0) * T_ + t0;
#pragma unroll
  for (int i = 0; i < 16; ++i) {
    const int c = rr + i * 4;
    tile[c][col] = xb[(size_t)c * T_ + col];
  }
  __syncthreads();
  unsigned short* ob = xbt + ((size_t)b * T_ + t0) * C_ + c0;
#pragma unroll
  for (int i = 0; i < 16; ++i) {
    const int t = rr + i * 4;
    ob[(size_t)t * C_ + col] = f2bf(tile[col][t]);
  }
}

// W [in][out] f32 -> Wt [out][in] bf16 ; z selects which weight
__global__ __launch_bounds__(256) void transpose_w(const float* __restrict__ Wq,
                                                   const float* __restrict__ Wk,
                                                   const float* __restrict__ Wv,
                                                   const float* __restrict__ Wo,
                                                   unsigned short* __restrict__ WcatT,
                                                   unsigned short* __restrict__ WoT) {
  const int w = blockIdx.z;
  const float* src = (w == 0) ? Wq : (w == 1) ? Wk : (w == 2) ? Wv : Wo;
  unsigned short* dst = (w < 3) ? (WcatT + (size_t)w * C_ * C_) : WoT;
  __shared__ float tile[64][65];
  const int tid = threadIdx.x;
  const int o0 = blockIdx.x * 64, c0 = blockIdx.y * 64;
  const int col = tid & 63, rr = tid >> 6;
#pragma unroll
  for (int i = 0; i < 16; ++i) {
    const int c = rr + i * 4;
    tile[c][col] = src[(size_t)(c0 + c) * C_ + o0 + col];
  }
  __syncthreads();
#pragma unroll
  for (int i = 0; i < 16; ++i) {
    const int o = rr + i * 4;
    dst[(size_t)(o0 + o) * C_ + c0 + col] = f2bf(tile[col][o]);
  }
}

__global__ __launch_bounds__(256) void make_bcat(const float* __restrict__ bq,
                                                 const float* __restrict__ bk,
                                                 const float* __restrict__ bv,
                                                 float* __restrict__ bcat) {
  const int i = blockIdx.x * 256 + threadIdx.x;
  if (i < C3_) {
    const float* s = (i < 1024) ? bq : (i < 2048) ? bk : bv;
    bcat[i] = s[i & 1023];
  }
}

// ---------------- K1: fused QKV projection GEMM ----------------
// qkv[b][t][o'] = sum_c xbt[b][t][c] * WcatT[o'][c] + bcat[o'] ; elu+1 on o'<2048
__global__ __launch_bounds__(256) void gemm_qkv(const unsigned short* __restrict__ A,
                                                const unsigned short* __restrict__ Bw,
                                                const float* __restrict__ bcat,
                                                unsigned short* __restrict__ qkv) {
  __shared__ unsigned short As[128 * 64];
  __shared__ unsigned short Bs[128 * 64];
  const int tid = threadIdx.x;
  const int b = blockIdx.z;
  const int m0 = blockIdx.y * 128;  // t tile
  const int n0 = blockIdx.x * 128;  // o' tile
  const unsigned short* Ab = A + ((size_t)b * T_ + m0) * C_;
  const unsigned short* Bb = Bw + (size_t)n0 * C_;

  f32x4 acc[4][4];
  const f32x4 fzero = {0.f, 0.f, 0.f, 0.f};
#pragma unroll
  for (int i = 0; i < 4; ++i)
#pragma unroll
    for (int j = 0; j < 4; ++j) acc[i][j] = fzero;

  const int lane = tid & 63;
  const int wid = tid >> 6;
  const int wm = (wid >> 1) * 64;
  const int wn = (wid & 1) * 64;
  const int lr = lane & 15;
  const int lg = lane >> 4;
  const int srow = tid >> 3;
  const int scol = (tid & 7) * 8;

  for (int kt = 0; kt < C_; kt += 64) {
    __syncthreads();
#pragma unroll
    for (int it = 0; it < 4; ++it) {
      gload16(Ab + (size_t)(srow + it * 32) * C_ + kt + scol, As + it * 2048 + tid * 8);
      gload16(Bb + (size_t)(srow + it * 32) * C_ + kt + scol, Bs + it * 2048 + tid * 8);
    }
    __syncthreads();
#pragma unroll
    for (int kk = 0; kk < 2; ++kk) {
      bf16x8 af[4], bg[4];
#pragma unroll
      for (int i = 0; i < 4; ++i)
        af[i] = *(const bf16x8*)(As + (wm + i * 16 + lr) * 64 + kk * 32 + lg * 8);
#pragma unroll
      for (int j = 0; j < 4; ++j)
        bg[j] = *(const bf16x8*)(Bs + (wn + j * 16 + lr) * 64 + kk * 32 + lg * 8);
#pragma unroll
      for (int i = 0; i < 4; ++i)
#pragma unroll
        for (int j = 0; j < 4; ++j)
          acc[i][j] = __builtin_amdgcn_mfma_f32_16x16x32_bf16(af[i], bg[j], acc[i][j], 0, 0, 0);
    }
  }

  unsigned short* Cb = qkv + ((size_t)b * T_ + m0) * C3_;
#pragma unroll
  for (int j = 0; j < 4; ++j) {
    const int coln = n0 + wn + j * 16 + lr;
    const float bias = bcat[coln];
    const bool do_elu = (coln < 2048);  // wave-uniform (16-aligned ranges)
#pragma unroll
    for (int i = 0; i < 4; ++i) {
#pragma unroll
      for (int r = 0; r < 4; ++r) {
        const int row = wm + i * 16 + lg * 4 + r;
        float v = acc[i][j][r] + bias;
        if (do_elu) v = (v > 0.f) ? (v + 1.f) : __expf(v);  // elu(v)+1
        Cb[(size_t)row * C3_ + coln] = f2bf(v);
      }
    }
  }
}

// ---------------- K2: kvT[e][d] = sum_t k[t][d]*v[t][e]; ksum[d] = sum_t k[t][d] ----
__global__ __launch_bounds__(256) void kv_reduce(const unsigned short* __restrict__ qkv,
                                                 float* __restrict__ kvT,
                                                 float* __restrict__ ksum) {
  __shared__ unsigned short ks[64 * 64];
  __shared__ unsigned short vs[64 * 64];
  const int tid = threadIdx.x;
  const int chunk = blockIdx.x, h = blockIdx.y, b = blockIdx.z;
  const int di = tid >> 4, ei = tid & 15;
  float acc[4][4];
  float ksa[4] = {0.f, 0.f, 0.f, 0.f};
#pragma unroll
  for (int a = 0; a < 4; ++a)
#pragma unroll
    for (int c = 0; c < 4; ++c) acc[a][c] = 0.f;

  const unsigned short* base = qkv + ((size_t)b * T_ + chunk * 512) * C3_;
  const int srow = tid >> 3, scol = (tid & 7) * 8;

  for (int sub = 0; sub < 8; ++sub) {
    __syncthreads();
#pragma unroll
    for (int it = 0; it < 2; ++it) {
      const unsigned short* g = base + (size_t)(sub * 64 + srow + it * 32) * C3_ + h * 64;
      gload16(g + 1024 + scol, ks + it * 2048 + tid * 8);
      gload16(g + 2048 + scol, vs + it * 2048 + tid * 8);
    }
    __syncthreads();
    for (int t = 0; t < 64; ++t) {
      const us4 ku = *(const us4*)(ks + t * 64 + di * 4);
      const us4 vu = *(const us4*)(vs + t * 64 + ei * 4);
      float kf[4], vf[4];
#pragma unroll
      for (int a = 0; a < 4; ++a) {
        kf[a] = b2f(ku[a]);
        vf[a] = b2f(vu[a]);
        ksa[a] += kf[a];
      }
#pragma unroll
      for (int a = 0; a < 4; ++a)
#pragma unroll
        for (int c = 0; c < 4; ++c) acc[a][c] += kf[a] * vf[c];
    }
  }
  float* kvbase = kvT + (size_t)((b * H_ + h) * D_) * D_;
#pragma unroll
  for (int c = 0; c < 4; ++c)
#pragma unroll
    for (int a = 0; a < 4; ++a)
      atomicAdd(&kvbase[(size_t)(ei * 4 + c) * D_ + di * 4 + a], acc[a][c]);
  if (ei == 0) {
#pragma unroll
    for (int a = 0; a < 4; ++a)
      atomicAdd(&ksum[(size_t)(b * H_ + h) * D_ + di * 4 + a], ksa[a]);
  }
}

// ---------------- K2b: z[b][t][h] = sum_d q[t][h*64+d] * ksum[b][h][d] -------------
__global__ __launch_bounds__(256) void z_kernel(const unsigned short* __restrict__ qkv,
                                                const float* __restrict__ ksum,
                                                float* __restrict__ zbuf) {
  const int lane = threadIdx.x & 63;
  const int wid = blockIdx.x * 4 + (threadIdx.x >> 6);
  for (int tt = wid; tt < B_ * T_; tt += 256 * 4) {
    const int b = tt >> 12;
    const unsigned short* qrow = qkv + (size_t)tt * C3_;  // q occupies cols [0,1024)
#pragma unroll
    for (int h = 0; h < H_; ++h) {
      float p = b2f(qrow[h * 64 + lane]) * ksum[(size_t)(b * H_ + h) * D_ + lane];
#pragma unroll
      for (int off = 32; off; off >>= 1) p += __shfl_xor(p, off);
      if (lane == 0) zbuf[(size_t)tt * H_ + h] = p;
    }
  }
}

// ---------------- K3: y[b][t][h*64+e] = (sum_d q[t][d]*kvT[e][d]) / (z+eps) --------
__global__ __launch_bounds__(256) void attn_apply(const unsigned short* __restrict__ qkv,
                                                  const float* __restrict__ kvT,
                                                  const float* __restrict__ zbuf,
                                                  unsigned short* __restrict__ y) {
  __shared__ unsigned short Qs[128 * 64];
  __shared__ unsigned short Ks2[64 * 64];
  const int tid = threadIdx.x;
  const int t0 = blockIdx.x * 128, h = blockIdx.y, b = blockIdx.z;
  const int srow = tid >> 3, scol = (tid & 7) * 8;

  // stage Q tile [128][64] (async)
#pragma unroll
  for (int it = 0; it < 4; ++it) {
    gload16(qkv + ((size_t)b * T_ + t0 + srow + it * 32) * C3_ + h * 64 + scol,
            Qs + it * 2048 + tid * 8);
  }
  // stage kvT -> bf16 [64 e][64 d]
  {
    const int e = tid >> 2, dblk = (tid & 3) * 16;
    const float* kvrow = kvT + ((size_t)(b * H_ + h) * D_ + e) * D_ + dblk;
    us8 w0, w1;
#pragma unroll
    for (int m = 0; m < 8; ++m) {
      w0[m] = f2bf(kvrow[m]);
      w1[m] = f2bf(kvrow[8 + m]);
    }
    *(us8*)(Ks2 + e * 64 + dblk) = w0;
    *(us8*)(Ks2 + e * 64 + dblk + 8) = w1;
  }
  __syncthreads();

  const int lane = tid & 63;
  const int wid = tid >> 6;
  const int lr = lane & 15, lg = lane >> 4;
  f32x4 acc[2][4];
  const f32x4 fzero = {0.f, 0.f, 0.f, 0.f};
#pragma unroll
  for (int i = 0; i < 2; ++i)
#pragma unroll
    for (int j = 0; j < 4; ++j) acc[i][j] = fzero;

#pragma unroll
  for (int kk = 0; kk < 2; ++kk) {
    bf16x8 aq[2], bk_[4];
#pragma unroll
    for (int i = 0; i < 2; ++i)
      aq[i] = *(const bf16x8*)(Qs + (wid * 32 + i * 16 + lr) * 64 + kk * 32 + lg * 8);
#pragma unroll
    for (int j = 0; j < 4; ++j)
      bk_[j] = *(const bf16x8*)(Ks2 + (j * 16 + lr) * 64 + kk * 32 + lg * 8);
#pragma unroll
    for (int i = 0; i < 2; ++i)
#pragma unroll
      for (int j = 0; j < 4; ++j)
        acc[i][j] = __builtin_amdgcn_mfma_f32_16x16x32_bf16(aq[i], bk_[j], acc[i][j], 0, 0, 0);
  }

#pragma unroll
  for (int i = 0; i < 2; ++i) {
#pragma unroll
    for (int r = 0; r < 4; ++r) {
      const int t = t0 + wid * 32 + i * 16 + lg * 4 + r;
      const float inv = 1.f / (zbuf[((size_t)b * T_ + t) * H_ + h] + 1e-6f);
      unsigned short* yrow = y + ((size_t)b * T_ + t) * C_ + h * 64;
#pragma unroll
      for (int j = 0; j < 4; ++j) {
        yrow[j * 16 + lr] = f2bf(acc[i][j][r] * inv);
      }
    }
  }
}

// ---------------- K4: out[b][o][t] = sum_c WoT[o][c]*y[b][t][c] + bo[o] + x[b][o][t]
__global__ __launch_bounds__(256) void gemm_out(const unsigned short* __restrict__ A,
                                                const unsigned short* __restrict__ Yb,
                                                const float* __restrict__ bo,
                                                const float* __restrict__ x,
                                                float* __restrict__ out) {
  __shared__ unsigned short As[128 * 64];
  __shared__ unsigned short Bs[128 * 64];
  const int tid = threadIdx.x;
  const int b = blockIdx.z;
  const int m0 = blockIdx.y * 128;  // o tile
  const int n0 = blockIdx.x * 128;  // t tile
  const unsigned short* Ab = A + (size_t)m0 * C_;
  const unsigned short* Bb = Yb + ((size_t)b * T_ + n0) * C_;

  f32x4 acc[4][4];
  const f32x4 fzero = {0.f, 0.f, 0.f, 0.f};
#pragma unroll
  for (int i = 0; i < 4; ++i)
#pragma unroll
    for (int j = 0; j < 4; ++j) acc[i][j] = fzero;

  const int lane = tid & 63;
  const int wid = tid >> 6;
  const int wm = (wid >> 1) * 64;
  const int wn = (wid & 1) * 64;
  const int lr = lane & 15;
  const int lg = lane >> 4;
  const int srow = tid >> 3;
  const int scol = (tid & 7) * 8;

  for (int kt = 0; kt < C_; kt += 64) {
    __syncthreads();
#pragma unroll
    for (int it = 0; it < 4; ++it) {
      gload16(Ab + (size_t)(srow + it * 32) * C_ + kt + scol, As + it * 2048 + tid * 8);
      gload16(Bb + (size_t)(srow + it * 32) * C_ + kt + scol, Bs + it * 2048 + tid * 8);
    }
    __syncthreads();
#pragma unroll
    for (int kk = 0; kk < 2; ++kk) {
      bf16x8 af[4], bg[4];
#pragma unroll
      for (int i = 0; i < 4; ++i)
        af[i] = *(const bf16x8*)(As + (wm + i * 16 + lr) * 64 + kk * 32 + lg * 8);
#pragma unroll
      for (int j = 0; j < 4; ++j)
        bg[j] = *(const bf16x8*)(Bs + (wn + j * 16 + lr) * 64 + kk * 32 + lg * 8);
#pragma unroll
      for (int i = 0; i < 4; ++i)
#pragma unroll
        for (int j = 0; j < 4; ++j)
          acc[i][j] = __builtin_amdgcn_mfma_f32_16x16x32_bf16(af[i], bg[j], acc[i][j], 0, 0, 0);
    }
  }

#pragma unroll
  for (int i = 0; i < 4; ++i) {
#pragma unroll
    for (int r = 0; r < 4; ++r) {
      const int o = m0 + wm + i * 16 + lg * 4 + r;
      const float bias = bo[o];
      const float* xrow = x + ((size_t)b * C_ + o) * T_ + n0;
      float* orow = out + ((size_t)b * C_ + o) * T_ + n0;
#pragma unroll
      for (int j = 0; j < 4; ++j) {
        const int t = wn + j * 16 + lr;
        orow[t] = acc[i][j][r] + bias + xrow[t];
      }
    }
  }
}

// ---------------- launch ----------------
extern "C" void kernel_launch(void* const* d_in, const int* in_sizes, int n_in,
                              void* d_out, int out_size, void* d_ws, size_t ws_size,
                              hipStream_t stream) {
  (void)in_sizes; (void)n_in; (void)out_size; (void)ws_size;
  const float* x  = (const float*)d_in[0];
  const float* Wq = (const float*)d_in[1];
  const float* bq = (const float*)d_in[2];
  const float* Wk = (const float*)d_in[3];
  const float* bk = (const float*)d_in[4];
  const float* Wv = (const float*)d_in[5];
  const float* bv = (const float*)d_in[6];
  const float* Wo = (const float*)d_in[7];
  const float* bo = (const float*)d_in[8];
  float* out = (float*)d_out;

  char* p = (char*)d_ws;
  unsigned short* xbt   = (unsigned short*)p; p += (size_t)B_ * T_ * C_ * 2;    // 67 MB
  unsigned short* qkv   = (unsigned short*)p; p += (size_t)B_ * T_ * C3_ * 2;   // 201 MB
  unsigned short* WcatT = (unsigned short*)p; p += (size_t)C3_ * C_ * 2;        // 6.3 MB
  unsigned short* WoT   = (unsigned short*)p; p += (size_t)C_ * C_ * 2;         // 2 MB
  float* bcat = (float*)p; p += (size_t)C3_ * 4;
  float* kvT  = (float*)p; p += (size_t)B_ * H_ * D_ * D_ * 4;                  // 2 MB
  float* ksum = (float*)p; p += (size_t)B_ * H_ * D_ * 4;
  float* zbuf = (float*)p; p += (size_t)B_ * T_ * H_ * 4;                       // 2 MB
  unsigned short* y = xbt;  // alias: xbt is dead after gemm_qkv

  // zero the atomic accumulators (kvT and ksum are adjacent)
  hipMemsetAsync(kvT, 0, (size_t)(B_ * H_ * D_ * D_ + B_ * H_ * D_) * 4, stream);

  transpose_x<<<dim3(T_ / 64, C_ / 64, B_), 256, 0, stream>>>(x, xbt);
  transpose_w<<<dim3(16, 16, 4), 256, 0, stream>>>(Wq, Wk, Wv, Wo, WcatT, WoT);
  make_bcat<<<dim3(12), 256, 0, stream>>>(bq, bk, bv, bcat);
  gemm_qkv<<<dim3(C3_ / 128, T_ / 128, B_), 256, 0, stream>>>(xbt, WcatT, bcat, qkv);
  kv_reduce<<<dim3(T_ / 512, H_, B_), 256, 0, stream>>>(qkv, kvT, ksum);
  z_kernel<<<dim3(256), 256, 0, stream>>>(qkv, ksum, zbuf);
  attn_apply<<<dim3(T_ / 128, H_, B_), 256, 0, stream>>>(qkv, kvT, zbuf, y);
  gemm_out<<<dim3(T_ / 128, C_ / 128, B_), 256, 0, stream>>>(WoT, y, bo, x, out);
}

// Round 5
// 584.181 us; speedup vs baseline: 1.4448x; 1.4448x over previous
//
#include <hip/hip_runtime.h>

#define B_  8
#define T_  4096
#define C_  1024
#define H_  16
#define D_  64
#define C3_ 3072

typedef __attribute__((ext_vector_type(4))) float f32x4;
typedef __attribute__((ext_vector_type(8))) __bf16 bf16x8;
typedef __attribute__((ext_vector_type(4))) unsigned short us4;
typedef __attribute__((ext_vector_type(8))) unsigned short us8;

__device__ __forceinline__ float b2f(unsigned short u) {
  return __uint_as_float(((unsigned)u) << 16);
}
__device__ __forceinline__ unsigned short f2bf(float f) {
  unsigned u = __float_as_uint(f);
  u += 0x7fffu + ((u >> 16) & 1u);
  return (unsigned short)(u >> 16);
}
__device__ __forceinline__ void gload16(const void* g, void* l) {
  __builtin_amdgcn_global_load_lds(
      (const __attribute__((address_space(1))) void*)g,
      (__attribute__((address_space(3))) void*)l, 16, 0, 0);
}

// ---------------- pre-passes ----------------

// x [B][C][T] f32 -> xbt [B][T][C] bf16
__global__ __launch_bounds__(256) void transpose_x(const float* __restrict__ x,
                                                   unsigned short* __restrict__ xbt) {
  __shared__ float tile[64][65];
  const int tid = threadIdx.x;
  const int t0 = blockIdx.x * 64, c0 = blockIdx.y * 64, b = blockIdx.z;
  const int col = tid & 63, rr = tid >> 6;
  const float* xb = x + ((size_t)b * C_ + c0) * T_ + t0;
#pragma unroll
  for (int i = 0; i < 16; ++i) {
    const int c = rr + i * 4;
    tile[c][col] = xb[(size_t)c * T_ + col];
  }
  __syncthreads();
  unsigned short* ob = xbt + ((size_t)b * T_ + t0) * C_ + c0;
#pragma unroll
  for (int i = 0; i < 16; ++i) {
    const int t = rr + i * 4;
    ob[(size_t)t * C_ + col] = f2bf(tile[col][t]);
  }
}

// W [in][out] f32 -> Wt [out][in] bf16
__global__ __launch_bounds__(256) void transpose_w(const float* __restrict__ Wq,
                                                   const float* __restrict__ Wk,
                                                   const float* __restrict__ Wv,
                                                   const float* __restrict__ Wo,
                                                   unsigned short* __restrict__ WcatT,
                                                   unsigned short* __restrict__ WoT) {
  const int w = blockIdx.z;
  const float* src = (w == 0) ? Wq : (w == 1) ? Wk : (w == 2) ? Wv : Wo;
  unsigned short* dst = (w < 3) ? (WcatT + (size_t)w * C_ * C_) : WoT;
  __shared__ float tile[64][65];
  const int tid = threadIdx.x;
  const int o0 = blockIdx.x * 64, c0 = blockIdx.y * 64;
  const int col = tid & 63, rr = tid >> 6;
#pragma unroll
  for (int i = 0; i < 16; ++i) {
    const int c = rr + i * 4;
    tile[c][col] = src[(size_t)(c0 + c) * C_ + o0 + col];
  }
  __syncthreads();
#pragma unroll
  for (int i = 0; i < 16; ++i) {
    const int o = rr + i * 4;
    dst[(size_t)(o0 + o) * C_ + c0 + col] = f2bf(tile[col][o]);
  }
}

__global__ __launch_bounds__(256) void make_bcat(const float* __restrict__ bq,
                                                 const float* __restrict__ bk,
                                                 const float* __restrict__ bv,
                                                 float* __restrict__ bcat) {
  const int i = blockIdx.x * 256 + threadIdx.x;
  if (i < C3_) {
    const float* s = (i < 1024) ? bq : (i < 2048) ? bk : bv;
    bcat[i] = s[i & 1023];
  }
}

// ---------------- K1: fused QKV projection GEMM ----------------
__global__ __launch_bounds__(256) void gemm_qkv(const unsigned short* __restrict__ A,
                                                const unsigned short* __restrict__ Bw,
                                                const float* __restrict__ bcat,
                                                unsigned short* __restrict__ qkv) {
  __shared__ unsigned short As[128 * 64];
  __shared__ unsigned short Bs[128 * 64];
  const int tid = threadIdx.x;
  const int b = blockIdx.z;
  const int m0 = blockIdx.y * 128;  // t tile
  const int n0 = blockIdx.x * 128;  // o' tile
  const unsigned short* Ab = A + ((size_t)b * T_ + m0) * C_;
  const unsigned short* Bb = Bw + (size_t)n0 * C_;

  f32x4 acc[4][4];
  const f32x4 fzero = {0.f, 0.f, 0.f, 0.f};
#pragma unroll
  for (int i = 0; i < 4; ++i)
#pragma unroll
    for (int j = 0; j < 4; ++j) acc[i][j] = fzero;

  const int lane = tid & 63;
  const int wid = tid >> 6;
  const int wm = (wid >> 1) * 64;
  const int wn = (wid & 1) * 64;
  const int lr = lane & 15;
  const int lg = lane >> 4;
  const int srow = tid >> 3;
  const int scol = (tid & 7) * 8;

  for (int kt = 0; kt < C_; kt += 64) {
    __syncthreads();
#pragma unroll
    for (int it = 0; it < 4; ++it) {
      gload16(Ab + (size_t)(srow + it * 32) * C_ + kt + scol, As + it * 2048 + tid * 8);
      gload16(Bb + (size_t)(srow + it * 32) * C_ + kt + scol, Bs + it * 2048 + tid * 8);
    }
    __syncthreads();
#pragma unroll
    for (int kk = 0; kk < 2; ++kk) {
      bf16x8 af[4], bg[4];
#pragma unroll
      for (int i = 0; i < 4; ++i)
        af[i] = *(const bf16x8*)(As + (wm + i * 16 + lr) * 64 + kk * 32 + lg * 8);
#pragma unroll
      for (int j = 0; j < 4; ++j)
        bg[j] = *(const bf16x8*)(Bs + (wn + j * 16 + lr) * 64 + kk * 32 + lg * 8);
#pragma unroll
      for (int i = 0; i < 4; ++i)
#pragma unroll
        for (int j = 0; j < 4; ++j)
          acc[i][j] = __builtin_amdgcn_mfma_f32_16x16x32_bf16(af[i], bg[j], acc[i][j], 0, 0, 0);
    }
  }

  unsigned short* Cb = qkv + ((size_t)b * T_ + m0) * C3_;
#pragma unroll
  for (int j = 0; j < 4; ++j) {
    const int coln = n0 + wn + j * 16 + lr;
    const float bias = bcat[coln];
    const bool do_elu = (coln < 2048);  // wave-uniform (16-aligned ranges)
#pragma unroll
    for (int i = 0; i < 4; ++i) {
#pragma unroll
      for (int r = 0; r < 4; ++r) {
        const int row = wm + i * 16 + lg * 4 + r;
        float v = acc[i][j][r] + bias;
        if (do_elu) v = (v > 0.f) ? (v + 1.f) : __expf(v);  // elu(v)+1
        Cb[(size_t)row * C3_ + coln] = f2bf(v);
      }
    }
  }
}

// ---------------- K2: kvT[e][d] = sum_t k[t][d]*v[t][e]; ksum[d] = sum_t k[t][d] ----
__global__ __launch_bounds__(256) void kv_reduce(const unsigned short* __restrict__ qkv,
                                                 float* __restrict__ kvT,
                                                 float* __restrict__ ksum) {
  __shared__ unsigned short ks[64 * 64];
  __shared__ unsigned short vs[64 * 64];
  const int tid = threadIdx.x;
  const int chunk = blockIdx.x, h = blockIdx.y, b = blockIdx.z;
  const int di = tid >> 4, ei = tid & 15;
  float acc[4][4];
  float ksa[4] = {0.f, 0.f, 0.f, 0.f};
#pragma unroll
  for (int a = 0; a < 4; ++a)
#pragma unroll
    for (int c = 0; c < 4; ++c) acc[a][c] = 0.f;

  const unsigned short* base = qkv + ((size_t)b * T_ + chunk * 512) * C3_;
  const int srow = tid >> 3, scol = (tid & 7) * 8;

  for (int sub = 0; sub < 8; ++sub) {
    __syncthreads();
#pragma unroll
    for (int it = 0; it < 2; ++it) {
      const unsigned short* g = base + (size_t)(sub * 64 + srow + it * 32) * C3_ + h * 64;
      gload16(g + 1024 + scol, ks + it * 2048 + tid * 8);
      gload16(g + 2048 + scol, vs + it * 2048 + tid * 8);
    }
    __syncthreads();
    for (int t = 0; t < 64; ++t) {
      const us4 ku = *(const us4*)(ks + t * 64 + di * 4);
      const us4 vu = *(const us4*)(vs + t * 64 + ei * 4);
      float kf[4], vf[4];
#pragma unroll
      for (int a = 0; a < 4; ++a) {
        kf[a] = b2f(ku[a]);
        vf[a] = b2f(vu[a]);
        ksa[a] += kf[a];
      }
#pragma unroll
      for (int a = 0; a < 4; ++a)
#pragma unroll
        for (int c = 0; c < 4; ++c) acc[a][c] += kf[a] * vf[c];
    }
  }
  float* kvbase = kvT + (size_t)((b * H_ + h) * D_) * D_;
#pragma unroll
  for (int c = 0; c < 4; ++c)
#pragma unroll
    for (int a = 0; a < 4; ++a)
      atomicAdd(&kvbase[(size_t)(ei * 4 + c) * D_ + di * 4 + a], acc[a][c]);
  if (ei == 0) {
#pragma unroll
    for (int a = 0; a < 4; ++a)
      atomicAdd(&ksum[(size_t)(b * H_ + h) * D_ + di * 4 + a], ksa[a]);
  }
}

// ---------------- K3: y = (q·kvT)/(q·ksum + eps), z fused via 5th B-fragment -------
__global__ __launch_bounds__(256) void attn_apply(const unsigned short* __restrict__ qkv,
                                                  const float* __restrict__ kvT,
                                                  const float* __restrict__ ksum,
                                                  unsigned short* __restrict__ y) {
  __shared__ unsigned short Qs[128 * 64];
  __shared__ unsigned short Ks2[80 * 64];  // rows 0-63: kvT[e][d]; row 64: ksum; 65-79: 0
  const int tid = threadIdx.x;
  const int t0 = blockIdx.x * 128, h = blockIdx.y, b = blockIdx.z;
  const int srow = tid >> 3, scol = (tid & 7) * 8;

  // stage Q tile [128][64] (async)
#pragma unroll
  for (int it = 0; it < 4; ++it) {
    gload16(qkv + ((size_t)b * T_ + t0 + srow + it * 32) * C3_ + h * 64 + scol,
            Qs + it * 2048 + tid * 8);
  }
  // stage kvT -> bf16 [64 e][64 d]
  {
    const int e = tid >> 2, dblk = (tid & 3) * 16;
    const float* kvrow = kvT + ((size_t)(b * H_ + h) * D_ + e) * D_ + dblk;
    us8 w0, w1;
#pragma unroll
    for (int m = 0; m < 8; ++m) {
      w0[m] = f2bf(kvrow[m]);
      w1[m] = f2bf(kvrow[8 + m]);
    }
    *(us8*)(Ks2 + e * 64 + dblk) = w0;
    *(us8*)(Ks2 + e * 64 + dblk + 8) = w1;
  }
  // row 64 = ksum (bf16), rows 65-79 = 0
  if (tid < 64) Ks2[64 * 64 + tid] = f2bf(ksum[(size_t)(b * H_ + h) * D_ + tid]);
  for (int i = tid; i < 15 * 64; i += 256) Ks2[65 * 64 + i] = 0;
  __syncthreads();

  const int lane = tid & 63;
  const int wid = tid >> 6;
  const int lr = lane & 15, lg = lane >> 4;
  f32x4 acc[2][4];
  f32x4 accz[2];
  const f32x4 fzero = {0.f, 0.f, 0.f, 0.f};
#pragma unroll
  for (int i = 0; i < 2; ++i) {
    accz[i] = fzero;
#pragma unroll
    for (int j = 0; j < 4; ++j) acc[i][j] = fzero;
  }

#pragma unroll
  for (int kk = 0; kk < 2; ++kk) {
    bf16x8 aq[2], bk_[4], b4;
#pragma unroll
    for (int i = 0; i < 2; ++i)
      aq[i] = *(const bf16x8*)(Qs + (wid * 32 + i * 16 + lr) * 64 + kk * 32 + lg * 8);
#pragma unroll
    for (int j = 0; j < 4; ++j)
      bk_[j] = *(const bf16x8*)(Ks2 + (j * 16 + lr) * 64 + kk * 32 + lg * 8);
    b4 = *(const bf16x8*)(Ks2 + (64 + lr) * 64 + kk * 32 + lg * 8);
#pragma unroll
    for (int i = 0; i < 2; ++i) {
#pragma unroll
      for (int j = 0; j < 4; ++j)
        acc[i][j] = __builtin_amdgcn_mfma_f32_16x16x32_bf16(aq[i], bk_[j], acc[i][j], 0, 0, 0);
      accz[i] = __builtin_amdgcn_mfma_f32_16x16x32_bf16(aq[i], b4, accz[i], 0, 0, 0);
    }
  }

#pragma unroll
  for (int i = 0; i < 2; ++i) {
#pragma unroll
    for (int r = 0; r < 4; ++r) {
      const int t = t0 + wid * 32 + i * 16 + lg * 4 + r;
      // z for row t lives in col 0 of the j=4 fragment -> lane (lg*16 + 0)
      const float zv = __shfl(accz[i][r], lane & 48);
      const float inv = 1.f / (zv + 1e-6f);
      unsigned short* yrow = y + ((size_t)b * T_ + t) * C_ + h * 64;
#pragma unroll
      for (int j = 0; j < 4; ++j) {
        yrow[j * 16 + lr] = f2bf(acc[i][j][r] * inv);
      }
    }
  }
}

// ---------------- K4: out[b][o][t] = sum_c WoT[o][c]*y[b][t][c] + bo[o] + x[b][o][t]
__global__ __launch_bounds__(256) void gemm_out(const unsigned short* __restrict__ A,
                                                const unsigned short* __restrict__ Yb,
                                                const float* __restrict__ bo,
                                                const float* __restrict__ x,
                                                float* __restrict__ out) {
  __shared__ unsigned short As[128 * 64];
  __shared__ unsigned short Bs[128 * 64];
  const int tid = threadIdx.x;
  const int b = blockIdx.z;
  const int m0 = blockIdx.y * 128;  // o tile
  const int n0 = blockIdx.x * 128;  // t tile
  const unsigned short* Ab = A + (size_t)m0 * C_;
  const unsigned short* Bb = Yb + ((size_t)b * T_ + n0) * C_;

  f32x4 acc[4][4];
  const f32x4 fzero = {0.f, 0.f, 0.f, 0.f};
#pragma unroll
  for (int i = 0; i < 4; ++i)
#pragma unroll
    for (int j = 0; j < 4; ++j) acc[i][j] = fzero;

  const int lane = tid & 63;
  const int wid = tid >> 6;
  const int wm = (wid >> 1) * 64;
  const int wn = (wid & 1) * 64;
  const int lr = lane & 15;
  const int lg = lane >> 4;
  const int srow = tid >> 3;
  const int scol = (tid & 7) * 8;

  for (int kt = 0; kt < C_; kt += 64) {
    __syncthreads();
#pragma unroll
    for (int it = 0; it < 4; ++it) {
      gload16(Ab + (size_t)(srow + it * 32) * C_ + kt + scol, As + it * 2048 + tid * 8);
      gload16(Bb + (size_t)(srow + it * 32) * C_ + kt + scol, Bs + it * 2048 + tid * 8);
    }
    __syncthreads();
#pragma unroll
    for (int kk = 0; kk < 2; ++kk) {
      bf16x8 af[4], bg[4];
#pragma unroll
      for (int i = 0; i < 4; ++i)
        af[i] = *(const bf16x8*)(As + (wm + i * 16 + lr) * 64 + kk * 32 + lg * 8);
#pragma unroll
      for (int j = 0; j < 4; ++j)
        bg[j] = *(const bf16x8*)(Bs + (wn + j * 16 + lr) * 64 + kk * 32 + lg * 8);
#pragma unroll
      for (int i = 0; i < 4; ++i)
#pragma unroll
        for (int j = 0; j < 4; ++j)
          acc[i][j] = __builtin_amdgcn_mfma_f32_16x16x32_bf16(af[i], bg[j], acc[i][j], 0, 0, 0);
    }
  }

#pragma unroll
  for (int i = 0; i < 4; ++i) {
#pragma unroll
    for (int r = 0; r < 4; ++r) {
      const int o = m0 + wm + i * 16 + lg * 4 + r;
      const float bias = bo[o];
      const float* xrow = x + ((size_t)b * C_ + o) * T_ + n0;
      float* orow = out + ((size_t)b * C_ + o) * T_ + n0;
#pragma unroll
      for (int j = 0; j < 4; ++j) {
        const int t = wn + j * 16 + lr;
        orow[t] = acc[i][j][r] + bias + xrow[t];
      }
    }
  }
}

// ---------------- launch ----------------
extern "C" void kernel_launch(void* const* d_in, const int* in_sizes, int n_in,
                              void* d_out, int out_size, void* d_ws, size_t ws_size,
                              hipStream_t stream) {
  (void)in_sizes; (void)n_in; (void)out_size; (void)ws_size;
  const float* x  = (const float*)d_in[0];
  const float* Wq = (const float*)d_in[1];
  const float* bq = (const float*)d_in[2];
  const float* Wk = (const float*)d_in[3];
  const float* bk = (const float*)d_in[4];
  const float* Wv = (const float*)d_in[5];
  const float* bv = (const float*)d_in[6];
  const float* Wo = (const float*)d_in[7];
  const float* bo = (const float*)d_in[8];
  float* out = (float*)d_out;

  char* p = (char*)d_ws;
  unsigned short* xbt   = (unsigned short*)p; p += (size_t)B_ * T_ * C_ * 2;    // 67 MB
  unsigned short* qkv   = (unsigned short*)p; p += (size_t)B_ * T_ * C3_ * 2;   // 201 MB
  unsigned short* WcatT = (unsigned short*)p; p += (size_t)C3_ * C_ * 2;        // 6.3 MB
  unsigned short* WoT   = (unsigned short*)p; p += (size_t)C_ * C_ * 2;         // 2 MB
  float* bcat = (float*)p; p += (size_t)C3_ * 4;
  float* kvT  = (float*)p; p += (size_t)B_ * H_ * D_ * D_ * 4;                  // 2 MB
  float* ksum = (float*)p; p += (size_t)B_ * H_ * D_ * 4;
  unsigned short* y = xbt;  // alias: xbt is dead after gemm_qkv

  // zero the atomic accumulators (kvT and ksum are adjacent)
  hipMemsetAsync(kvT, 0, (size_t)(B_ * H_ * D_ * D_ + B_ * H_ * D_) * 4, stream);

  transpose_x<<<dim3(T_ / 64, C_ / 64, B_), 256, 0, stream>>>(x, xbt);
  transpose_w<<<dim3(16, 16, 4), 256, 0, stream>>>(Wq, Wk, Wv, Wo, WcatT, WoT);
  make_bcat<<<dim3(12), 256, 0, stream>>>(bq, bk, bv, bcat);
  gemm_qkv<<<dim3(C3_ / 128, T_ / 128, B_), 256, 0, stream>>>(xbt, WcatT, bcat, qkv);
  kv_reduce<<<dim3(T_ / 512, H_, B_), 256, 0, stream>>>(qkv, kvT, ksum);
  attn_apply<<<dim3(T_ / 128, H_, B_), 256, 0, stream>>>(qkv, kvT, ksum, y);
  gemm_out<<<dim3(T_ / 128, C_ / 128, B_), 256, 0, stream>>>(WoT, y, bo, x, out);
}